// Round 2
// baseline (200.588 us; speedup 1.0000x reference)
//
#include <hip/hip_runtime.h>

typedef float v2f __attribute__((ext_vector_type(2)));
typedef float v4f __attribute__((ext_vector_type(4)));

#define IMG_H 1080
#define IMG_W 1920
#define NBATCH 8
#define LSTRIP 9             // output rows per lane (R10: back to 9)
#define BROWS (4*LSTRIP)     // 36 rows per block
#define NK (LSTRIP+4)        // 13 schedule rows
#define PF 4                 // prefetch distance (rows ahead)
#define RS 5                 // raw-row ring slots (PF+1)

// R10: "TLP, not per-wave pipelining" — R9 showed the kernel is
// latency-bound: VALUBusy 48%, HBM 34%, OccupancyPercent 29.9% at
// VGPR=60 (grid 960 = 3.75 blocks/CU = 2.4 waves/SIMD avg; HW allows 8
// waves/SIMD at this VGPR count). R8 (1920 blocks) held 13 rows in
// flight -> high VGPR capped waves; R9 (ring) had low VGPR but few
// blocks. This round combines them: LSTRIP=9 (grid 1920 = 7.5
// blocks/CU), shallow PF=4 ring (20 VGPRs payload),
// launch_bounds(256,6) as spill guardrail -> expect ~60 VGPRs and 6-8
// waves/SIMD resident. Latency hiding via wave interleave, not per-wave
// prefetch depth. Edge algebra identical to validated R7/R8/R9.

static __device__ __forceinline__ v2f vfma2(v2f a, v2f b, v2f c) {
    return __builtin_elementwise_fma(a, b, c);
}
static __device__ __forceinline__ float bperm(int addr, float v) {
    return __int_as_float(__builtin_amdgcn_ds_bpermute(addr, __float_as_int(v)));
}

__global__ __launch_bounds__(256, 6)
void shi_tomasi_kernel(const float* __restrict__ img, float* __restrict__ out) {
    const int cg    = threadIdx.x & 63;            // lane within wave
    const int strip = threadIdx.x >> 6;            // wave-uniform 0..3
    const int bx    = blockIdx.x;
    const int base  = bx * 240;
    const int cl    = min(max(base - 8 + 4 * cg, 0), IMG_W - 4);  // load col
    const int c0    = base + 4 * (cg - 2);         // output col (lanes 2..61)
    const int s0    = blockIdx.y * BROWS + strip * LSTRIP;
    const float* g  = img + (size_t)blockIdx.z * (IMG_H * IMG_W);
    float* outb     = out + (size_t)blockIdx.z * (IMG_H * IMG_W);

    const bool eL     = (bx == 0) && (cg == 2);    // c0 == 0
    const bool eR     = (bx == 7) && (cg == 61);   // c0 == W-4
    const bool doSt   = (cg >= 2) && (cg < 62);
    const int  aLft   = 4 * (cg - 1);
    const int  aRgt   = 4 * (cg + 1);
    const bool topFix = (s0 == 0);                 // wave-uniform
    const bool botFix = (s0 + LSTRIP == IMG_H);    // wave-uniform

    const float* lp = g + cl;

    // ---- preload first PF raw rows into the ring ----
    v4f Zr[RS];
    #pragma unroll
    for (int k = 0; k < PF; ++k) {
        int lr = s0 - 2 + k;                       // wave-uniform -> scalar
        lr = max(0, min(IMG_H - 1, lr));
        Zr[k % RS] = *(const v4f*)(lp + (size_t)lr * IMG_W);
    }

    v2f hdR[3][3], hsR[3][3];
    float hfd[3], hfs[3];
    v2f hxx[3][2], hyy[3][2], hxy[3][2];
    const v2f two = {2.0f, 2.0f};

    #pragma unroll
    for (int k = 0; k < NK; ++k) {
        // ---- rolling prefetch: issue load for row k+PF ----
        if (k + PF < NK) {
            int lr = s0 - 2 + k + PF;              // wave-uniform -> scalar
            lr = max(0, min(IMG_H - 1, lr));
            Zr[(k + PF) % RS] = *(const v4f*)(lp + (size_t)lr * IMG_W);
        }

        // ---- separable partials for schedule row k ----
        {
            const v4f Z = Zr[k % RS];
            const float zl0 = bperm(aLft, Z.z), zl1 = bperm(aLft, Z.w);
            const float zr0 = bperm(aRgt, Z.x), zr1 = bperm(aRgt, Z.y);
            v2f Z0 = v2f{zl0, zl1};
            if (eL) Z0 = v2f{Z.x, Z.x};            // replicate col 0
            const v2f Z1 = v2f{Z.x, Z.y};
            const v2f Z2 = v2f{Z.z, Z.w};
            v2f Z3 = v2f{zr0, zr1};
            if (eR) Z3 = v2f{Z.w, Z.w};            // replicate col W-1

            const v2f Sab = v2f{Z0.y, Z1.x};
            const v2f Sbc = v2f{Z1.y, Z2.x};
            const v2f Scd = v2f{Z2.y, Z3.x};
            v2f* hd = hdR[k % 3];
            v2f* hs = hsR[k % 3];
            hd[0] = Z1 - Z0; hd[1] = Z2 - Z1; hd[2] = Z3 - Z2;
            hs[0] = vfma2(Sab, two, Z0) + Z1;
            hs[1] = vfma2(Sbc, two, Z1) + Z2;
            hs[2] = vfma2(Scd, two, Z2) + Z3;
            // double-clamped edge-col partials (virtual col -1 / col W)
            hfd[k % 3] = eR ? (Z2.y - Z2.x) : (Z1.y - Z1.x);
            hfs[k % 3] = eR ? (Z2.x + 3.0f * Z2.y) : (3.0f * Z1.x + Z1.y);
        }

        // ---- product row vr = s0-1+(k-2) (k>=2) ----
        if (k >= 2) {
            const int rr = k - 2;
            const int sm = rr % 3, sz = (rr + 1) % 3, sp = (rr + 2) % 3;

            v2f Ixp[3], Iyp[3];
            #pragma unroll
            for (int j = 0; j < 3; ++j) {
                Ixp[j] = vfma2(hdR[sz][j], two, hdR[sm][j]) + hdR[sp][j];
                Iyp[j] = hsR[sp][j] - hsR[sm][j];
            }
            const float ixf = hfd[sm] + 2.0f * hfd[sz] + hfd[sp];
            const float iyf = hfs[sp] - hfs[sm];
            if (eL) { Ixp[0].x = ixf; Iyp[0].x = iyf; }
            if (eR) { Ixp[2].y = ixf; Iyp[2].y = iyf; }

            v2f xx[3], yy[3], xy[3];
            #pragma unroll
            for (int j = 0; j < 3; ++j) {
                xx[j] = Ixp[j] * Ixp[j];
                yy[j] = Iyp[j] * Iyp[j];
                xy[j] = Ixp[j] * Iyp[j];
            }
            {
                v2f* hx = hxx[rr % 3];
                v2f* hy = hyy[rr % 3];
                v2f* hz = hxy[rr % 3];
                hx[0] = xx[0] + v2f{xx[0].y, xx[1].x} + xx[1];
                hx[1] = xx[1] + v2f{xx[1].y, xx[2].x} + xx[2];
                hy[0] = yy[0] + v2f{yy[0].y, yy[1].x} + yy[1];
                hy[1] = yy[1] + v2f{yy[1].y, yy[2].x} + yy[2];
                hz[0] = xy[0] + v2f{xy[0].y, xy[1].x} + xy[1];
                hz[1] = xy[1] + v2f{xy[1].y, xy[2].x} + xy[2];
            }
            if (rr == 1 && topFix) {               // P(-1) == P(0)
                #pragma unroll
                for (int q = 0; q < 2; ++q) {
                    hxx[0][q] = hxx[1][q]; hyy[0][q] = hyy[1][q]; hxy[0][q] = hxy[1][q];
                }
            }
            if (rr == LSTRIP + 1 && botFix) {      // P(H) == P(H-1)
                #pragma unroll
                for (int q = 0; q < 2; ++q) {
                    hxx[rr % 3][q] = hxx[(rr - 1) % 3][q];
                    hyy[rr % 3][q] = hyy[(rr - 1) % 3][q];
                    hxy[rr % 3][q] = hxy[(rr - 1) % 3][q];
                }
            }

            if (rr >= 2) {
                const int a = (rr - 2) % 3, b2 = (rr - 1) % 3, c = rr % 3;
                float rv[4];
                #pragma unroll
                for (int q = 0; q < 2; ++q) {
                    const v2f sxx = hxx[a][q] + hxx[b2][q] + hxx[c][q];
                    const v2f syy = hyy[a][q] + hyy[b2][q] + hyy[c][q];
                    const v2f sxy = hxy[a][q] + hxy[b2][q] + hxy[c][q];
                    const v2f S = sxx + syy;
                    const v2f D = sxx - syy;
                    const v2f E = sxy + sxy;
                    const v2f disc = vfma2(D, D, vfma2(E, E, v2f{4e-10f, 4e-10f}));
                    const v2f qv = {__builtin_sqrtf(disc.x), __builtin_sqrtf(disc.y)};
                    const v2f lam = (S - qv) * 0.5f;
                    rv[2 * q]     = fmaxf(lam.x, 0.0f);
                    rv[2 * q + 1] = fmaxf(lam.y, 0.0f);
                }
                if (doSt) {
                    float* orowp = outb + (size_t)(s0 + rr - 2) * IMG_W + c0;
                    __builtin_nontemporal_store(v4f{rv[0], rv[1], rv[2], rv[3]},
                                                (v4f*)orowp);
                }
            }
        }
    }
}

extern "C" void kernel_launch(void* const* d_in, const int* in_sizes, int n_in,
                              void* d_out, int out_size, void* d_ws, size_t ws_size,
                              hipStream_t stream) {
    const float* img = (const float*)d_in[0];
    float* out = (float*)d_out;
    dim3 grid(8, IMG_H / BROWS, NBATCH);           // 8 x 30 x 8 = 1920 blocks
    shi_tomasi_kernel<<<grid, 256, 0, stream>>>(img, out);
}

// Round 3
// 117.044 us; speedup vs baseline: 1.7138x; 1.7138x over previous
//
#include <hip/hip_runtime.h>

typedef float v2f __attribute__((ext_vector_type(2)));
typedef float v4f __attribute__((ext_vector_type(4)));

#define IMG_H 1080
#define IMG_W 1920
#define NBATCH 8
#define LSTRIP 9             // output rows per lane
#define BROWS (4*LSTRIP)     // 36 rows per block
#define NK (LSTRIP+4)        // 13 schedule rows
#define PF 4                 // prefetch distance (rows ahead)
#define RS 5                 // raw-row ring slots (PF+1)

// R11: R10 minus the spill. R10's launch_bounds(256,6) forced VGPR=40 ->
// scratch spills (FETCH 181MB vs 46MB input, WRITE 196MB vs 65MB output)
// -> 122us. The TLP theory was never tested. This round: same LSTRIP=9 /
// grid-1920 / PF=4 ring, but launch_bounds(256,3) like validated R9 ->
// expect ~60 VGPRs (R9's identical structure at LSTRIP=18 compiled to 60),
// no spill, and HW-allowed 8 waves/SIMD with 7.5 blocks/CU resident.
// launch_bounds 2nd arg is a MINIMUM guarantee, not a cap — occupancy
// above it comes free from the low natural VGPR count.
// Edge algebra identical to validated R7/R8/R9.

static __device__ __forceinline__ v2f vfma2(v2f a, v2f b, v2f c) {
    return __builtin_elementwise_fma(a, b, c);
}
static __device__ __forceinline__ float bperm(int addr, float v) {
    return __int_as_float(__builtin_amdgcn_ds_bpermute(addr, __float_as_int(v)));
}

__global__ __launch_bounds__(256, 3)
void shi_tomasi_kernel(const float* __restrict__ img, float* __restrict__ out) {
    const int cg    = threadIdx.x & 63;            // lane within wave
    const int strip = threadIdx.x >> 6;            // wave-uniform 0..3
    const int bx    = blockIdx.x;
    const int base  = bx * 240;
    const int cl    = min(max(base - 8 + 4 * cg, 0), IMG_W - 4);  // load col
    const int c0    = base + 4 * (cg - 2);         // output col (lanes 2..61)
    const int s0    = blockIdx.y * BROWS + strip * LSTRIP;
    const float* g  = img + (size_t)blockIdx.z * (IMG_H * IMG_W);
    float* outb     = out + (size_t)blockIdx.z * (IMG_H * IMG_W);

    const bool eL     = (bx == 0) && (cg == 2);    // c0 == 0
    const bool eR     = (bx == 7) && (cg == 61);   // c0 == W-4
    const bool doSt   = (cg >= 2) && (cg < 62);
    const int  aLft   = 4 * (cg - 1);
    const int  aRgt   = 4 * (cg + 1);
    const bool topFix = (s0 == 0);                 // wave-uniform
    const bool botFix = (s0 + LSTRIP == IMG_H);    // wave-uniform

    const float* lp = g + cl;

    // ---- preload first PF raw rows into the ring ----
    v4f Zr[RS];
    #pragma unroll
    for (int k = 0; k < PF; ++k) {
        int lr = s0 - 2 + k;                       // wave-uniform -> scalar
        lr = max(0, min(IMG_H - 1, lr));
        Zr[k % RS] = *(const v4f*)(lp + (size_t)lr * IMG_W);
    }

    v2f hdR[3][3], hsR[3][3];
    float hfd[3], hfs[3];
    v2f hxx[3][2], hyy[3][2], hxy[3][2];
    const v2f two = {2.0f, 2.0f};

    #pragma unroll
    for (int k = 0; k < NK; ++k) {
        // ---- rolling prefetch: issue load for row k+PF ----
        if (k + PF < NK) {
            int lr = s0 - 2 + k + PF;              // wave-uniform -> scalar
            lr = max(0, min(IMG_H - 1, lr));
            Zr[(k + PF) % RS] = *(const v4f*)(lp + (size_t)lr * IMG_W);
        }

        // ---- separable partials for schedule row k ----
        {
            const v4f Z = Zr[k % RS];
            const float zl0 = bperm(aLft, Z.z), zl1 = bperm(aLft, Z.w);
            const float zr0 = bperm(aRgt, Z.x), zr1 = bperm(aRgt, Z.y);
            v2f Z0 = v2f{zl0, zl1};
            if (eL) Z0 = v2f{Z.x, Z.x};            // replicate col 0
            const v2f Z1 = v2f{Z.x, Z.y};
            const v2f Z2 = v2f{Z.z, Z.w};
            v2f Z3 = v2f{zr0, zr1};
            if (eR) Z3 = v2f{Z.w, Z.w};            // replicate col W-1

            const v2f Sab = v2f{Z0.y, Z1.x};
            const v2f Sbc = v2f{Z1.y, Z2.x};
            const v2f Scd = v2f{Z2.y, Z3.x};
            v2f* hd = hdR[k % 3];
            v2f* hs = hsR[k % 3];
            hd[0] = Z1 - Z0; hd[1] = Z2 - Z1; hd[2] = Z3 - Z2;
            hs[0] = vfma2(Sab, two, Z0) + Z1;
            hs[1] = vfma2(Sbc, two, Z1) + Z2;
            hs[2] = vfma2(Scd, two, Z2) + Z3;
            // double-clamped edge-col partials (virtual col -1 / col W)
            hfd[k % 3] = eR ? (Z2.y - Z2.x) : (Z1.y - Z1.x);
            hfs[k % 3] = eR ? (Z2.x + 3.0f * Z2.y) : (3.0f * Z1.x + Z1.y);
        }

        // ---- product row vr = s0-1+(k-2) (k>=2) ----
        if (k >= 2) {
            const int rr = k - 2;
            const int sm = rr % 3, sz = (rr + 1) % 3, sp = (rr + 2) % 3;

            v2f Ixp[3], Iyp[3];
            #pragma unroll
            for (int j = 0; j < 3; ++j) {
                Ixp[j] = vfma2(hdR[sz][j], two, hdR[sm][j]) + hdR[sp][j];
                Iyp[j] = hsR[sp][j] - hsR[sm][j];
            }
            const float ixf = hfd[sm] + 2.0f * hfd[sz] + hfd[sp];
            const float iyf = hfs[sp] - hfs[sm];
            if (eL) { Ixp[0].x = ixf; Iyp[0].x = iyf; }
            if (eR) { Ixp[2].y = ixf; Iyp[2].y = iyf; }

            v2f xx[3], yy[3], xy[3];
            #pragma unroll
            for (int j = 0; j < 3; ++j) {
                xx[j] = Ixp[j] * Ixp[j];
                yy[j] = Iyp[j] * Iyp[j];
                xy[j] = Ixp[j] * Iyp[j];
            }
            {
                v2f* hx = hxx[rr % 3];
                v2f* hy = hyy[rr % 3];
                v2f* hz = hxy[rr % 3];
                hx[0] = xx[0] + v2f{xx[0].y, xx[1].x} + xx[1];
                hx[1] = xx[1] + v2f{xx[1].y, xx[2].x} + xx[2];
                hy[0] = yy[0] + v2f{yy[0].y, yy[1].x} + yy[1];
                hy[1] = yy[1] + v2f{yy[1].y, yy[2].x} + yy[2];
                hz[0] = xy[0] + v2f{xy[0].y, xy[1].x} + xy[1];
                hz[1] = xy[1] + v2f{xy[1].y, xy[2].x} + xy[2];
            }
            if (rr == 1 && topFix) {               // P(-1) == P(0)
                #pragma unroll
                for (int q = 0; q < 2; ++q) {
                    hxx[0][q] = hxx[1][q]; hyy[0][q] = hyy[1][q]; hxy[0][q] = hxy[1][q];
                }
            }
            if (rr == LSTRIP + 1 && botFix) {      // P(H) == P(H-1)
                #pragma unroll
                for (int q = 0; q < 2; ++q) {
                    hxx[rr % 3][q] = hxx[(rr - 1) % 3][q];
                    hyy[rr % 3][q] = hyy[(rr - 1) % 3][q];
                    hxy[rr % 3][q] = hxy[(rr - 1) % 3][q];
                }
            }

            if (rr >= 2) {
                const int a = (rr - 2) % 3, b2 = (rr - 1) % 3, c = rr % 3;
                float rv[4];
                #pragma unroll
                for (int q = 0; q < 2; ++q) {
                    const v2f sxx = hxx[a][q] + hxx[b2][q] + hxx[c][q];
                    const v2f syy = hyy[a][q] + hyy[b2][q] + hyy[c][q];
                    const v2f sxy = hxy[a][q] + hxy[b2][q] + hxy[c][q];
                    const v2f S = sxx + syy;
                    const v2f D = sxx - syy;
                    const v2f E = sxy + sxy;
                    const v2f disc = vfma2(D, D, vfma2(E, E, v2f{4e-10f, 4e-10f}));
                    const v2f qv = {__builtin_sqrtf(disc.x), __builtin_sqrtf(disc.y)};
                    const v2f lam = (S - qv) * 0.5f;
                    rv[2 * q]     = fmaxf(lam.x, 0.0f);
                    rv[2 * q + 1] = fmaxf(lam.y, 0.0f);
                }
                if (doSt) {
                    float* orowp = outb + (size_t)(s0 + rr - 2) * IMG_W + c0;
                    __builtin_nontemporal_store(v4f{rv[0], rv[1], rv[2], rv[3]},
                                                (v4f*)orowp);
                }
            }
        }
    }
}

extern "C" void kernel_launch(void* const* d_in, const int* in_sizes, int n_in,
                              void* d_out, int out_size, void* d_ws, size_t ws_size,
                              hipStream_t stream) {
    const float* img = (const float*)d_in[0];
    float* out = (float*)d_out;
    dim3 grid(8, IMG_H / BROWS, NBATCH);           // 8 x 30 x 8 = 1920 blocks
    shi_tomasi_kernel<<<grid, 256, 0, stream>>>(img, out);
}